// Round 1
// baseline (359.214 us; speedup 1.0000x reference)
//
#include <hip/hip_runtime.h>

typedef _Float16 f16;
typedef _Float16 f16x8 __attribute__((ext_vector_type(8)));
typedef _Float16 f16x4 __attribute__((ext_vector_type(4)));
typedef float f32x4 __attribute__((ext_vector_type(4)));

#define S_TOK 4096
#define NB 2
#define NH 8
#define DKH 64
#define DMODEL 512

static __device__ __forceinline__ f32x4 mfma16(f16x8 a, f16x8 b, f32x4 c) {
    return __builtin_amdgcn_mfma_f32_16x16x32_f16(a, b, c, 0, 0, 0);
}

// ---------------- projection: out = x @ W^T  (x:[8192][512] f32, W:[512][512] f32)
// MODE 0 = Q (scaled by 1/8, layout [bh][s][dk])
// MODE 1 = K (layout [bh][s][dk])
// MODE 2 = V (layout [bh][dk][s]  -- transposed for PV B-operand)
template<int MODE>
__global__ __launch_bounds__(256)
void proj_kernel(const float* __restrict__ x, const float* __restrict__ W,
                 f16* __restrict__ out)
{
    __shared__ f16 As[128 * 40];   // 128 rows x 32 k, stride 40 halves (80B, 16B-aligned, conflict-light)
    __shared__ f16 Bs[128 * 40];
    const int m0 = blockIdx.x * 128;
    const int n0 = blockIdx.y * 128;
    const int tid = threadIdx.x;
    const int wv = tid >> 6;
    const int lane = tid & 63;
    const int lr = lane & 15, lg = lane >> 4;
    const int wm = (wv >> 1) * 64, wn = (wv & 1) * 64;

    f32x4 acc[4][4];
#pragma unroll
    for (int i = 0; i < 4; ++i)
#pragma unroll
        for (int j = 0; j < 4; ++j) acc[i][j] = f32x4{0.f, 0.f, 0.f, 0.f};

    for (int kb = 0; kb < DMODEL; kb += 32) {
#pragma unroll
        for (int c = 0; c < 2; ++c) {
            const int chunk = tid + c * 256;
            const int row = chunk >> 2;
            const int col = (chunk & 3) * 8;
            const float* ga = x + (size_t)(m0 + row) * DMODEL + kb + col;
            float4 a0 = *(const float4*)ga;
            float4 a1 = *(const float4*)(ga + 4);
            f16x8 ha = { (f16)a0.x, (f16)a0.y, (f16)a0.z, (f16)a0.w,
                         (f16)a1.x, (f16)a1.y, (f16)a1.z, (f16)a1.w };
            *(f16x8*)(As + row * 40 + col) = ha;
            const float* gb = W + (size_t)(n0 + row) * DMODEL + kb + col;
            float4 b0 = *(const float4*)gb;
            float4 b1 = *(const float4*)(gb + 4);
            f16x8 hb = { (f16)b0.x, (f16)b0.y, (f16)b0.z, (f16)b0.w,
                         (f16)b1.x, (f16)b1.y, (f16)b1.z, (f16)b1.w };
            *(f16x8*)(Bs + row * 40 + col) = hb;
        }
        __syncthreads();
        f16x8 af[4], bf[4];
#pragma unroll
        for (int i = 0; i < 4; ++i)
            af[i] = *(const f16x8*)(As + (wm + 16 * i + lr) * 40 + 8 * lg);
#pragma unroll
        for (int j = 0; j < 4; ++j)
            bf[j] = *(const f16x8*)(Bs + (wn + 16 * j + lr) * 40 + 8 * lg);
#pragma unroll
        for (int i = 0; i < 4; ++i)
#pragma unroll
            for (int j = 0; j < 4; ++j)
                acc[i][j] = mfma16(af[i], bf[j], acc[i][j]);
        __syncthreads();
    }

#pragma unroll
    for (int i = 0; i < 4; ++i) {
        const int mbase = m0 + wm + 16 * i + 4 * lg;   // + reg r
#pragma unroll
        for (int j = 0; j < 4; ++j) {
            const int n = n0 + wn + 16 * j + lr;
            const int h = n >> 6, dk = n & 63;
            if (MODE == 2) {
                const int b = mbase >> 12;
                const int s = mbase & 4095;       // s..s+3 contiguous via regs
                f16x4 v4;
#pragma unroll
                for (int r = 0; r < 4; ++r) v4[r] = (f16)acc[i][j][r];
                *(f16x4*)(out + ((size_t)(b * NH + h) * DKH + dk) * S_TOK + s) = v4;
            } else {
#pragma unroll
                for (int r = 0; r < 4; ++r) {
                    const int m = mbase + r;
                    const int b = m >> 12, s = m & 4095;
                    const float sc = (MODE == 0) ? 0.125f : 1.0f;  // 1/sqrt(64) folded into Q
                    out[((size_t)(b * NH + h) * S_TOK + s) * DKH + dk] = (f16)(acc[i][j][r] * sc);
                }
            }
        }
    }
}

// ---------------- causal flash attention, one (bh, 64-row q-tile) per block, 4 waves
__global__ __launch_bounds__(256)
void attn_kernel(const f16* __restrict__ qh, const f16* __restrict__ kh,
                 const f16* __restrict__ vt, f16* __restrict__ ctx)
{
    __shared__ f16 Ks[64 * 72];       // [kv][dk], stride 72 halves
    __shared__ f16 Vs[64 * 72];       // [dk][kv]
    __shared__ f16 Ps[4 * 16 * 72];   // per-wave [16 q][64 kv]
    const int bh = blockIdx.y;
    const int q0 = blockIdx.x * 64;
    const int tid = threadIdx.x, wv = tid >> 6, lane = tid & 63;
    const int lr = lane & 15, lg = lane >> 4;
    const f16* Qp = qh + (size_t)bh * S_TOK * DKH;
    const f16* Kp = kh + (size_t)bh * S_TOK * DKH;
    const f16* Vp = vt + (size_t)bh * DKH * S_TOK;

    // Q fragments (this wave's 16 rows), held in registers for the whole loop
    f16x8 aq[2];
    aq[0] = *(const f16x8*)(Qp + (size_t)(q0 + 16 * wv + lr) * DKH + 8 * lg);
    aq[1] = *(const f16x8*)(Qp + (size_t)(q0 + 16 * wv + lr) * DKH + 32 + 8 * lg);

    f32x4 acco[4];  // ctx accumulator: 4 dk-fragments x 4 q-rows(regs)
#pragma unroll
    for (int c = 0; c < 4; ++c) acco[c] = f32x4{0.f, 0.f, 0.f, 0.f};
    float mrow[4], lrow[4];
#pragma unroll
    for (int r = 0; r < 4; ++r) { mrow[r] = -1e30f; lrow[r] = 0.f; }

    const int tlast = q0 >> 6;
    for (int t = 0; t <= tlast; ++t) {
        const int kv0 = t * 64;
        __syncthreads();  // all waves done reading Ks/Vs from previous tile
#pragma unroll
        for (int c2 = 0; c2 < 2; ++c2) {
            const int chunk = tid + c2 * 256;
            const int row = chunk >> 3;
            const int col = (chunk & 7) * 8;
            *(f16x8*)(Ks + row * 72 + col) =
                *(const f16x8*)(Kp + (size_t)(kv0 + row) * DKH + col);
            *(f16x8*)(Vs + row * 72 + col) =
                *(const f16x8*)(Vp + (size_t)row * S_TOK + kv0 + col);
        }
        __syncthreads();

        // scores: S = Q (16q x 64dk) x K^T (64dk x 64kv), D rows = q(4*lg+r), cols = kv(16c+lr)
        f32x4 sc[4];
#pragma unroll
        for (int c = 0; c < 4; ++c) sc[c] = f32x4{0.f, 0.f, 0.f, 0.f};
#pragma unroll
        for (int c = 0; c < 4; ++c)
#pragma unroll
            for (int kk = 0; kk < 2; ++kk) {
                f16x8 bf = *(const f16x8*)(Ks + (16 * c + lr) * 72 + 32 * kk + 8 * lg);
                sc[c] = mfma16(aq[kk], bf, sc[c]);
            }

        if (t == tlast) {  // causal mask on the diagonal tile only
#pragma unroll
            for (int c = 0; c < 4; ++c) {
                const int kvg = kv0 + 16 * c + lr;
#pragma unroll
                for (int r = 0; r < 4; ++r) {
                    const int qg = q0 + 16 * wv + 4 * lg + r;
                    if (kvg > qg) sc[c][r] = -1e30f;
                }
            }
        }

        // online softmax per q-row (r); row spans 4 frags (in-lane) x 16 lanes (lr)
#pragma unroll
        for (int r = 0; r < 4; ++r) {
            float tm = fmaxf(fmaxf(sc[0][r], sc[1][r]), fmaxf(sc[2][r], sc[3][r]));
            tm = fmaxf(tm, __shfl_xor(tm, 1));
            tm = fmaxf(tm, __shfl_xor(tm, 2));
            tm = fmaxf(tm, __shfl_xor(tm, 4));
            tm = fmaxf(tm, __shfl_xor(tm, 8));
            const float mn = fmaxf(mrow[r], tm);
            const float p0 = __expf(sc[0][r] - mn);
            const float p1 = __expf(sc[1][r] - mn);
            const float p2 = __expf(sc[2][r] - mn);
            const float p3 = __expf(sc[3][r] - mn);
            float ts = p0 + p1 + p2 + p3;
            ts += __shfl_xor(ts, 1);
            ts += __shfl_xor(ts, 2);
            ts += __shfl_xor(ts, 4);
            ts += __shfl_xor(ts, 8);
            const float sf = __expf(mrow[r] - mn);
            lrow[r] = lrow[r] * sf + ts;
            mrow[r] = mn;
#pragma unroll
            for (int c = 0; c < 4; ++c) acco[c][r] *= sf;
            f16* pw = Ps + (size_t)(wv * 16 + 4 * lg + r) * 72;
            pw[lr]      = (f16)p0;
            pw[16 + lr] = (f16)p1;
            pw[32 + lr] = (f16)p2;
            pw[48 + lr] = (f16)p3;
        }

        // PV: ctx += P(16q x 64kv) x V(64kv x 64dk); P read/write same wave -> DS pipe in-order
#pragma unroll
        for (int kk = 0; kk < 2; ++kk) {
            f16x8 ap = *(const f16x8*)(Ps + (size_t)(wv * 16 + lr) * 72 + 32 * kk + 8 * lg);
#pragma unroll
            for (int c = 0; c < 4; ++c) {
                f16x8 bvv = *(const f16x8*)(Vs + (16 * c + lr) * 72 + 32 * kk + 8 * lg);
                acco[c] = mfma16(ap, bvv, acco[c]);
            }
        }
    }

    const int b = bh >> 3, h = bh & 7;
#pragma unroll
    for (int c = 0; c < 4; ++c)
#pragma unroll
        for (int r = 0; r < 4; ++r) {
            const int q = q0 + 16 * wv + 4 * lg + r;
            const int dk = 16 * c + lr;
            ctx[((size_t)(b * S_TOK + q)) * DMODEL + h * DKH + dk] = (f16)(acco[c][r] / lrow[r]);
        }
}

// ---------------- output projection: out = ctx(f16) @ W_o^T + b_o, fp32 out
__global__ __launch_bounds__(256)
void oproj_kernel(const f16* __restrict__ A, const float* __restrict__ W,
                  const float* __restrict__ bias, float* __restrict__ out)
{
    __shared__ f16 As[128 * 40];
    __shared__ f16 Bs[128 * 40];
    const int m0 = blockIdx.x * 128;
    const int n0 = blockIdx.y * 128;
    const int tid = threadIdx.x;
    const int wv = tid >> 6;
    const int lane = tid & 63;
    const int lr = lane & 15, lg = lane >> 4;
    const int wm = (wv >> 1) * 64, wn = (wv & 1) * 64;

    f32x4 acc[4][4];
#pragma unroll
    for (int i = 0; i < 4; ++i)
#pragma unroll
        for (int j = 0; j < 4; ++j) acc[i][j] = f32x4{0.f, 0.f, 0.f, 0.f};

    for (int kb = 0; kb < DMODEL; kb += 32) {
#pragma unroll
        for (int c = 0; c < 2; ++c) {
            const int chunk = tid + c * 256;
            const int row = chunk >> 2;
            const int col = (chunk & 3) * 8;
            *(f16x8*)(As + row * 40 + col) =
                *(const f16x8*)(A + (size_t)(m0 + row) * DMODEL + kb + col);
            const float* gb = W + (size_t)(n0 + row) * DMODEL + kb + col;
            float4 b0 = *(const float4*)gb;
            float4 b1 = *(const float4*)(gb + 4);
            f16x8 hb = { (f16)b0.x, (f16)b0.y, (f16)b0.z, (f16)b0.w,
                         (f16)b1.x, (f16)b1.y, (f16)b1.z, (f16)b1.w };
            *(f16x8*)(Bs + row * 40 + col) = hb;
        }
        __syncthreads();
        f16x8 af[4], bf[4];
#pragma unroll
        for (int i = 0; i < 4; ++i)
            af[i] = *(const f16x8*)(As + (wm + 16 * i + lr) * 40 + 8 * lg);
#pragma unroll
        for (int j = 0; j < 4; ++j)
            bf[j] = *(const f16x8*)(Bs + (wn + 16 * j + lr) * 40 + 8 * lg);
#pragma unroll
        for (int i = 0; i < 4; ++i)
#pragma unroll
            for (int j = 0; j < 4; ++j)
                acc[i][j] = mfma16(af[i], bf[j], acc[i][j]);
        __syncthreads();
    }

#pragma unroll
    for (int i = 0; i < 4; ++i) {
        const int mbase = m0 + wm + 16 * i + 4 * lg;
#pragma unroll
        for (int j = 0; j < 4; ++j) {
            const int n = n0 + wn + 16 * j + lr;
            const float bn = bias[n];
#pragma unroll
            for (int r = 0; r < 4; ++r) {
                const int m = mbase + r;
                out[(size_t)m * DMODEL + n] = acc[i][j][r] + bn;
            }
        }
    }
}

extern "C" void kernel_launch(void* const* d_in, const int* in_sizes, int n_in,
                              void* d_out, int out_size, void* d_ws, size_t ws_size,
                              hipStream_t stream) {
    const float* q  = (const float*)d_in[0];
    const float* k  = (const float*)d_in[1];
    const float* v  = (const float*)d_in[2];
    const float* Wq = (const float*)d_in[3];
    const float* Wk = (const float*)d_in[4];
    const float* Wv = (const float*)d_in[5];
    const float* Wo = (const float*)d_in[6];
    const float* bo = (const float*)d_in[7];
    float* out = (float*)d_out;

    const size_t per = (size_t)NB * NH * S_TOK * DKH;   // 4,194,304 f16 elems
    f16* qh  = (f16*)d_ws;
    f16* kh  = qh + per;
    f16* vt  = kh + per;
    f16* ctx = vt + per;

    dim3 g(64, 4), blk(256);
    proj_kernel<0><<<g, blk, 0, stream>>>(q, Wq, qh);
    proj_kernel<1><<<g, blk, 0, stream>>>(k, Wk, kh);
    proj_kernel<2><<<g, blk, 0, stream>>>(v, Wv, vt);
    attn_kernel<<<dim3(S_TOK / 64, NB * NH), blk, 0, stream>>>(qh, kh, vt, ctx);
    oproj_kernel<<<g, blk, 0, stream>>>(ctx, Wo, bo, out);
}

// Round 2
// 125.000 us; speedup vs baseline: 2.8737x; 2.8737x over previous
//
#include <hip/hip_runtime.h>

typedef _Float16 f16;
typedef _Float16 f16x8 __attribute__((ext_vector_type(8)));
typedef _Float16 f16x4 __attribute__((ext_vector_type(4)));
typedef float f32x4 __attribute__((ext_vector_type(4)));

#define S_TOK 4096
#define NB 2
#define NH 8
#define DKH 64
#define DMODEL 512

static __device__ __forceinline__ f32x4 mfma16(f16x8 a, f16x8 b, f32x4 c) {
    return __builtin_amdgcn_mfma_f32_16x16x32_f16(a, b, c, 0, 0, 0);
}

// ---------------- fused QKV projection: out = x @ W^T (x:[8192][512] f32, W:[512][512] f32)
// mode 0 = Q (scaled 1/8, [bh][s][dk]); 1 = K ([bh][s][dk]); 2 = V ([bh][dk][s] transposed)
__global__ __launch_bounds__(256)
void proj_fused_kernel(const float* __restrict__ qx, const float* __restrict__ kx,
                       const float* __restrict__ vx,
                       const float* __restrict__ Wqp, const float* __restrict__ Wkp,
                       const float* __restrict__ Wvp,
                       f16* __restrict__ qo, f16* __restrict__ ko, f16* __restrict__ vo)
{
    const int mode = blockIdx.z;
    const float* x = (mode == 0) ? qx : (mode == 1) ? kx : vx;
    const float* W = (mode == 0) ? Wqp : (mode == 1) ? Wkp : Wvp;
    f16* out = (mode == 0) ? qo : (mode == 1) ? ko : vo;

    __shared__ f16 As[128 * 40];
    __shared__ f16 Bs[128 * 40];
    const int m0 = blockIdx.x * 128;
    const int n0 = blockIdx.y * 128;
    const int tid = threadIdx.x;
    const int wv = tid >> 6;
    const int lane = tid & 63;
    const int lr = lane & 15, lg = lane >> 4;
    const int wm = (wv >> 1) * 64, wn = (wv & 1) * 64;

    f32x4 acc[4][4];
#pragma unroll
    for (int i = 0; i < 4; ++i)
#pragma unroll
        for (int j = 0; j < 4; ++j) acc[i][j] = f32x4{0.f, 0.f, 0.f, 0.f};

    for (int kb = 0; kb < DMODEL; kb += 32) {
#pragma unroll
        for (int c = 0; c < 2; ++c) {
            const int chunk = tid + c * 256;
            const int row = chunk >> 2;
            const int col = (chunk & 3) * 8;
            const float* ga = x + (size_t)(m0 + row) * DMODEL + kb + col;
            float4 a0 = *(const float4*)ga;
            float4 a1 = *(const float4*)(ga + 4);
            f16x8 ha = { (f16)a0.x, (f16)a0.y, (f16)a0.z, (f16)a0.w,
                         (f16)a1.x, (f16)a1.y, (f16)a1.z, (f16)a1.w };
            *(f16x8*)(As + row * 40 + col) = ha;
            const float* gb = W + (size_t)(n0 + row) * DMODEL + kb + col;
            float4 b0 = *(const float4*)gb;
            float4 b1 = *(const float4*)(gb + 4);
            f16x8 hb = { (f16)b0.x, (f16)b0.y, (f16)b0.z, (f16)b0.w,
                         (f16)b1.x, (f16)b1.y, (f16)b1.z, (f16)b1.w };
            *(f16x8*)(Bs + row * 40 + col) = hb;
        }
        __syncthreads();
        f16x8 af[4], bf[4];
#pragma unroll
        for (int i = 0; i < 4; ++i)
            af[i] = *(const f16x8*)(As + (wm + 16 * i + lr) * 40 + 8 * lg);
#pragma unroll
        for (int j = 0; j < 4; ++j)
            bf[j] = *(const f16x8*)(Bs + (wn + 16 * j + lr) * 40 + 8 * lg);
#pragma unroll
        for (int i = 0; i < 4; ++i)
#pragma unroll
            for (int j = 0; j < 4; ++j)
                acc[i][j] = mfma16(af[i], bf[j], acc[i][j]);
        __syncthreads();
    }

#pragma unroll
    for (int i = 0; i < 4; ++i) {
        const int mbase = m0 + wm + 16 * i + 4 * lg;
#pragma unroll
        for (int j = 0; j < 4; ++j) {
            const int n = n0 + wn + 16 * j + lr;
            const int h = n >> 6, dk = n & 63;
            if (mode == 2) {
                const int b = mbase >> 12;
                const int s = mbase & 4095;
                f16x4 v4;
#pragma unroll
                for (int r = 0; r < 4; ++r) v4[r] = (f16)acc[i][j][r];
                *(f16x4*)(out + ((size_t)(b * NH + h) * DKH + dk) * S_TOK + s) = v4;
            } else {
                const float sc = (mode == 0) ? 0.125f : 1.0f;
#pragma unroll
                for (int r = 0; r < 4; ++r) {
                    const int m = mbase + r;
                    const int b = m >> 12, s = m & 4095;
                    out[((size_t)(b * NH + h) * S_TOK + s) * DKH + dk] = (f16)(acc[i][j][r] * sc);
                }
            }
        }
    }
}

// ---------------- causal flash attention, swapped-operand, QBLK=128 (8 waves), paired q-tiles
__global__ __launch_bounds__(512)
void attn_kernel(const f16* __restrict__ qh, const f16* __restrict__ kh,
                 const f16* __restrict__ vt, f16* __restrict__ ctx)
{
    __shared__ f16 Ks[2][64 * 64];    // linear [kv][dk], XOR-swizzled 16B granules
    __shared__ f16 Vs[2][64 * 64];    // linear [dk][kv], XOR-swizzled
    __shared__ f16 Ps[8][16 * 72];    // per-wave [q][kv], stride 72

    const int bid = blockIdx.x;
    const int remap = (bid & 7) * 32 + (bid >> 3);   // XCD-bijective (256 % 8 == 0)
    const int bh = remap >> 4;
    const int pair = remap & 15;
    const int tid = threadIdx.x, wv = tid >> 6, lane = tid & 63;
    const int lr = lane & 15, lg = lane >> 4;

    const f16* Qp = qh + (size_t)bh * S_TOK * DKH;
    const f16* Kp = kh + (size_t)bh * S_TOK * DKH;
    const f16* Vp = vt + (size_t)bh * DKH * S_TOK;
    const int b = bh >> 3, h = bh & 7;

    // staging: thread g -> row g>>3, LDS granule g&7 holds global granule (g&7)^(row&7)
    const int srow = tid >> 3;                  // 0..63
    const int sgr = (tid & 7) ^ (srow & 7);
    const f16* Kgb = Kp + srow * DKH + sgr * 8;
    const f16* Vgb = Vp + (size_t)srow * S_TOK + sgr * 8;
    const int ldst = srow * 64 + (tid & 7) * 8;
    f16* Pw = &Ps[wv][0];

    for (int seg = 0; seg < 2; ++seg) {
        const int qt = seg ? (31 - pair) : pair;     // work-balanced pair
        const int q0 = qt * 128;
        const int nt = (q0 >> 6) + 2;
        const int qrow = q0 + 16 * wv + lr;

        f16x8 aq0 = *(const f16x8*)(Qp + (size_t)qrow * DKH + 8 * lg);
        f16x8 aq1 = *(const f16x8*)(Qp + (size_t)qrow * DKH + 32 + 8 * lg);

        f32x4 acco[4];
#pragma unroll
        for (int c = 0; c < 4; ++c) acco[c] = f32x4{0.f, 0.f, 0.f, 0.f};
        float mrow = -1e30f, lrow = 0.f;

        // stage tile 0
        f16x8 kst = *(const f16x8*)Kgb;
        f16x8 vst = *(const f16x8*)Vgb;
        __syncthreads();                 // prior segment fully done with both buffers
        *(f16x8*)(&Ks[0][ldst]) = kst;
        *(f16x8*)(&Vs[0][ldst]) = vst;

        int cur = 0;
        for (int t = 0; t < nt; ++t) {
            const bool pre = (t + 1 < nt);
            if (pre) {                   // issue next-tile global loads early (T14)
                kst = *(const f16x8*)(Kgb + (size_t)(t + 1) * 64 * DKH);
                vst = *(const f16x8*)(Vgb + (t + 1) * 64);
            }
            __syncthreads();             // buf[cur] staged writes visible; buf[cur^1] free
            const f16* Kb = &Ks[cur][0];
            const f16* Vb = &Vs[cur][0];

            // S^T = K x Q^T : D[kv=16c+4lg+r][q=lr]
            f32x4 sc[4];
#pragma unroll
            for (int c = 0; c < 4; ++c) {
                const int row = 16 * c + lr;
                const int rs = row & 7;
                f16x8 ak0 = *(const f16x8*)(Kb + row * 64 + ((lg ^ rs) * 8));
                f16x8 ak1 = *(const f16x8*)(Kb + row * 64 + (((lg + 4) ^ rs) * 8));
                sc[c] = mfma16(ak0, aq0, f32x4{0.f, 0.f, 0.f, 0.f});
                sc[c] = mfma16(ak1, aq1, sc[c]);
            }

            if (t >= nt - 2) {           // diagonal tiles: causal mask
#pragma unroll
                for (int c = 0; c < 4; ++c)
#pragma unroll
                    for (int r = 0; r < 4; ++r) {
                        const int kvg = t * 64 + 16 * c + 4 * lg + r;
                        sc[c][r] = (kvg > qrow) ? -1e30f : sc[c][r];
                    }
            }

            // online softmax: kv-axis = 16 in-lane + lanes {xor16, xor32}
            float tm = -1e30f;
#pragma unroll
            for (int c = 0; c < 4; ++c) {
                float m01 = fmaxf(fmaxf(sc[c][0], sc[c][1]), fmaxf(sc[c][2], sc[c][3]));
                tm = fmaxf(tm, m01);
            }
            tm = fmaxf(tm, __shfl_xor(tm, 16));
            tm = fmaxf(tm, __shfl_xor(tm, 32));
            const float mn = fmaxf(mrow, tm);
            const float sf = __expf(mrow - mn);
            float ts = 0.f;
            float pv[4][4];
#pragma unroll
            for (int c = 0; c < 4; ++c)
#pragma unroll
                for (int r = 0; r < 4; ++r) {
                    const float p = __expf(sc[c][r] - mn);
                    pv[c][r] = p;
                    ts += p;
                }
            ts += __shfl_xor(ts, 16);
            ts += __shfl_xor(ts, 32);
            lrow = lrow * sf + ts;
            mrow = mn;
#pragma unroll
            for (int c = 0; c < 4; ++c) acco[c] *= sf;

            // P -> f16 -> per-wave LDS [q=lr][kv]
#pragma unroll
            for (int c = 0; c < 4; ++c) {
                f16x4 pk;
#pragma unroll
                for (int r = 0; r < 4; ++r) pk[r] = (f16)pv[c][r];
                *(f16x4*)(Pw + lr * 72 + 16 * c + 4 * lg) = pk;
            }
            f16x8 bp0 = *(const f16x8*)(Pw + lr * 72 + 8 * lg);
            f16x8 bp1 = *(const f16x8*)(Pw + lr * 72 + 32 + 8 * lg);

            // ctx^T += V^T x P^T : D[dk=16c+4lg+r][q=lr]
#pragma unroll
            for (int c = 0; c < 4; ++c) {
                const int row = 16 * c + lr;
                const int rs = row & 7;
                f16x8 av0 = *(const f16x8*)(Vb + row * 64 + ((lg ^ rs) * 8));
                f16x8 av1 = *(const f16x8*)(Vb + row * 64 + (((lg + 4) ^ rs) * 8));
                acco[c] = mfma16(av0, bp0, acco[c]);
                acco[c] = mfma16(av1, bp1, acco[c]);
            }

            if (pre) {                   // write prefetched tile into the other buffer
                *(f16x8*)(&Ks[cur ^ 1][ldst]) = kst;
                *(f16x8*)(&Vs[cur ^ 1][ldst]) = vst;
            }
            cur ^= 1;
        }

        const float invl = 1.0f / lrow;
        f16* cp = ctx + ((size_t)(b * S_TOK + qrow)) * DMODEL + h * DKH;
#pragma unroll
        for (int c = 0; c < 4; ++c) {
            f16x4 o;
#pragma unroll
            for (int r = 0; r < 4; ++r) o[r] = (f16)(acco[c][r] * invl);
            *(f16x4*)(cp + 16 * c + 4 * lg) = o;
        }
    }
}

// ---------------- output projection: out = ctx(f16) @ W_o^T + b_o, fp32 out
__global__ __launch_bounds__(256)
void oproj_kernel(const f16* __restrict__ A, const float* __restrict__ W,
                  const float* __restrict__ bias, float* __restrict__ out)
{
    __shared__ f16 As[128 * 40];
    __shared__ f16 Bs[128 * 40];
    const int m0 = blockIdx.x * 128;
    const int n0 = blockIdx.y * 128;
    const int tid = threadIdx.x;
    const int wv = tid >> 6;
    const int lane = tid & 63;
    const int lr = lane & 15, lg = lane >> 4;
    const int wm = (wv >> 1) * 64, wn = (wv & 1) * 64;

    f32x4 acc[4][4];
#pragma unroll
    for (int i = 0; i < 4; ++i)
#pragma unroll
        for (int j = 0; j < 4; ++j) acc[i][j] = f32x4{0.f, 0.f, 0.f, 0.f};

    for (int kb = 0; kb < DMODEL; kb += 32) {
#pragma unroll
        for (int c = 0; c < 2; ++c) {
            const int chunk = tid + c * 256;
            const int row = chunk >> 2;
            const int col = (chunk & 3) * 8;
            *(f16x8*)(As + row * 40 + col) =
                *(const f16x8*)(A + (size_t)(m0 + row) * DMODEL + kb + col);
            const float* gb = W + (size_t)(n0 + row) * DMODEL + kb + col;
            float4 b0 = *(const float4*)gb;
            float4 b1 = *(const float4*)(gb + 4);
            f16x8 hb = { (f16)b0.x, (f16)b0.y, (f16)b0.z, (f16)b0.w,
                         (f16)b1.x, (f16)b1.y, (f16)b1.z, (f16)b1.w };
            *(f16x8*)(Bs + row * 40 + col) = hb;
        }
        __syncthreads();
        f16x8 af[4], bf[4];
#pragma unroll
        for (int i = 0; i < 4; ++i)
            af[i] = *(const f16x8*)(As + (wm + 16 * i + lr) * 40 + 8 * lg);
#pragma unroll
        for (int j = 0; j < 4; ++j)
            bf[j] = *(const f16x8*)(Bs + (wn + 16 * j + lr) * 40 + 8 * lg);
#pragma unroll
        for (int i = 0; i < 4; ++i)
#pragma unroll
            for (int j = 0; j < 4; ++j)
                acc[i][j] = mfma16(af[i], bf[j], acc[i][j]);
        __syncthreads();
    }

#pragma unroll
    for (int i = 0; i < 4; ++i) {
        const int mbase = m0 + wm + 16 * i + 4 * lg;
#pragma unroll
        for (int j = 0; j < 4; ++j) {
            const int n = n0 + wn + 16 * j + lr;
            const float bn = bias[n];
#pragma unroll
            for (int r = 0; r < 4; ++r) {
                const int m = mbase + r;
                out[(size_t)m * DMODEL + n] = acc[i][j][r] + bn;
            }
        }
    }
}

extern "C" void kernel_launch(void* const* d_in, const int* in_sizes, int n_in,
                              void* d_out, int out_size, void* d_ws, size_t ws_size,
                              hipStream_t stream) {
    const float* q  = (const float*)d_in[0];
    const float* k  = (const float*)d_in[1];
    const float* v  = (const float*)d_in[2];
    const float* Wq = (const float*)d_in[3];
    const float* Wk = (const float*)d_in[4];
    const float* Wv = (const float*)d_in[5];
    const float* Wo = (const float*)d_in[6];
    const float* bo = (const float*)d_in[7];
    float* out = (float*)d_out;

    const size_t per = (size_t)NB * NH * S_TOK * DKH;
    f16* qh  = (f16*)d_ws;
    f16* kh  = qh + per;
    f16* vt  = kh + per;
    f16* ctx = vt + per;

    proj_fused_kernel<<<dim3(64, 4, 3), 256, 0, stream>>>(q, k, v, Wq, Wk, Wv, qh, kh, vt);
    attn_kernel<<<dim3(256), 512, 0, stream>>>(qh, kh, vt, ctx);
    oproj_kernel<<<dim3(64, 4), 256, 0, stream>>>(ctx, Wo, bo, out);
}